// Round 7
// baseline (129.174 us; speedup 1.0000x reference)
//
#include <hip/hip_runtime.h>

// QuantizedBKCore: tridiagonal resolvent diagonal via two continued-fraction
// sweeps, bit-exact vs numpy float32/complex64 reference (validated R1-R17:
// absmax == 0).
//
// R19 = R18 rerun (previous bench died on container infra, no signal).
// One robustness tweak: fma2() wrapper does per-component __builtin_fmaf
// instead of __builtin_elementwise_fma — identical semantics, identical
// packing opportunity (LLVM re-vectorizes adjacent identical scalar ops
// into v_pk_fma_f32), avoids any toolchain edge on the elementwise builtin.
//
// Theory (R18): R12-R17 showed VALUBusy x dur ~ 29-30k VALU-us across SIX
// schedule variants — issue-slot count is the cost; scheduling/occupancy
// levers are exhausted (occupancy pinned ~50%, launch_bounds hint ignored).
// Cut issue slots with gfx950 packed dual-f32 VALU (v_pk_fma/mul/add_f32):
// the warmup's two chains (bwd||fwd) and the forward main's two npdivs
// (combine||advance) are independent chains running IDENTICAL op
// sequences -> expressed as ext_vector_type(2) float pairs. Per component
// the ops are exactly fmaf/mul/add/sub as before; rcp, cmp/sel stay scalar
// per-component => BIT-EXACT by construction. Bwd main (single serial
// chain, no pair partner) stays scalar this round. Staging, batched LDS
// reads, per-8 64-B burst stores: identical to R17.

#define SEG    16                 // elements per lane
#define WCHEAP 16                 // approximate warmup steps (rcp-based)
#define WEXACT 8                  // exact Smith-tail steps
#define WARM   (WCHEAP + WEXACT)  // 24 total; HALO multiple of 4
#define LANES  64                 // lanes per wave
#define WAVES  4                  // waves (chunks) per block
#define NTHR   (LANES * WAVES)    // 256 threads per block
#define CHUNK  (LANES*SEG)        // 1024 elements per wave-chunk
#define BCHUNK (WAVES * CHUNK)    // 4096 elements per block
#define HALO   WARM
#define BSTAGE (BCHUNK + 2*HALO)  // 4144 staged negA values (shared halos)
#define SPAD   (BSTAGE + BSTAGE/32 + 1)  // stride-33 padding (2-way only: free)

typedef float f32x2 __attribute__((ext_vector_type(2)));

struct C2 { float r, i; };

__device__ __forceinline__ f32x2 mk2(float a, float b) {
  f32x2 r; r[0] = a; r[1] = b; return r;
}

// per-component fmaf on a float pair; LLVM packs adjacent pairs into
// v_pk_fma_f32 on gfx950 (worst case: same two scalar v_fma_f32 as before).
__device__ __forceinline__ f32x2 fma2(f32x2 a, f32x2 b, f32x2 c) {
  f32x2 r;
  r[0] = __builtin_fmaf(a[0], b[0], c[0]);
  r[1] = __builtin_fmaf(a[1], b[1], c[1]);
  return r;
}

__device__ __forceinline__ int padi(int i) { return i + (i >> 5); }

// ---------------- scalar exact path (unchanged from R12-R17) --------------

// IEEE-correctly-rounded f32 divide for mid-range normal operands.
// Exactly the Newton core of LLVM's gfx9 fdiv expansion; div_scale/div_fixup
// are identity for den in [~0.7, 26], num <= 130 (all values arising here),
// so the result is bit-identical to the compiler's a/b (= numpy's divide).
__device__ __forceinline__ float fdiv_ieee(float num, float den) {
  const float r0 = __builtin_amdgcn_rcpf(den);
  const float e0 = __builtin_fmaf(-den, r0, 1.0f);
  const float r1 = __builtin_fmaf(e0, r0, r0);
  const float q0 = num * r1;
  const float e1 = __builtin_fmaf(-den, q0, num);
  const float q1 = __builtin_fmaf(e1, r1, q0);
  const float e2 = __builtin_fmaf(-den, q1, num);
  return __builtin_fmaf(e2, r1, q1);
}

// numpy CFLOAT_divide (Smith), numerator (nr, 0), no FMA contraction in the
// surrounding mul/add ops (explicit fmaf inside fdiv_ieee is intentional).
__device__ __forceinline__ C2 npdiv(float nr, float dr, float di) {
  #pragma clang fp contract(off)
  const bool  b   = fabsf(dr) >= fabsf(di);
  const float num = b ? di : dr;
  const float den = b ? dr : di;
  const float rat = fdiv_ieee(num, den);  // == IEEE num/den (range-proven)
  const float t   = num * rat;
  const float s   = den + t;              // mul + add, NOT fma
  const float scl = fdiv_ieee(1.0f, s);   // == IEEE 1/s
  const float u   = nr * scl;
  const float m   = nr * rat;
  const float w   = m * scl;
  C2 o;
  o.r = b ? u : w;
  o.i = b ? -w : -u;                      // sign-of-product flip is exact
  return o;
}

// exact continued-fraction step: carry <- cv / (z - a - carry), z = i
__device__ __forceinline__ void cf_step(float na, float cv, float& cr, float& ci) {
  #pragma clang fp contract(off)
  const float dr = na - cr;
  const float di = 1.0f - ci;
  const C2 nc = npdiv(cv, dr, di);
  cr = nc.r; ci = nc.i;
}

// ---------------- packed (2-wide) exact path ------------------------------
// Component semantics are EXACTLY the scalar path: fma2 == fmaf per
// component, vector *,+,- are per-component IEEE ops, rcp is done scalar
// per component. Bit-exact vs scalar by construction.

__device__ __forceinline__ f32x2 fdiv2_ieee(f32x2 num, f32x2 den) {
  #pragma clang fp contract(off)
  f32x2 r0;
  r0[0] = __builtin_amdgcn_rcpf(den[0]);
  r0[1] = __builtin_amdgcn_rcpf(den[1]);
  const f32x2 one = mk2(1.0f, 1.0f);
  const f32x2 e0 = fma2(-den, r0, one);
  const f32x2 r1 = fma2(e0, r0, r0);
  const f32x2 q0 = num * r1;
  const f32x2 e1 = fma2(-den, q0, num);
  const f32x2 q1 = fma2(e1, r1, q0);
  const f32x2 e2 = fma2(-den, q1, num);
  return fma2(e2, r1, q1);
}

// two independent numpy CFLOAT_divides, packed 2-wide.
__device__ __forceinline__ void npdiv2(f32x2 nr, f32x2 dr, f32x2 di,
                                       f32x2& outr, f32x2& outi) {
  #pragma clang fp contract(off)
  const bool b0 = fabsf(dr[0]) >= fabsf(di[0]);
  const bool b1 = fabsf(dr[1]) >= fabsf(di[1]);
  f32x2 num, den;
  num[0] = b0 ? di[0] : dr[0];  den[0] = b0 ? dr[0] : di[0];
  num[1] = b1 ? di[1] : dr[1];  den[1] = b1 ? dr[1] : di[1];
  const f32x2 rat = fdiv2_ieee(num, den);
  const f32x2 t   = num * rat;
  const f32x2 s   = den + t;              // mul + add, NOT fma
  const f32x2 scl = fdiv2_ieee(mk2(1.0f, 1.0f), s);
  const f32x2 u   = nr * scl;
  const f32x2 m   = nr * rat;
  const f32x2 w   = m * scl;
  outr[0] = b0 ? u[0] : w[0];   outi[0] = b0 ? -w[0] : -u[0];
  outr[1] = b1 ? u[1] : w[1];   outi[1] = b1 ? -w[1] : -u[1];
}

// two independent exact CF steps, packed.
__device__ __forceinline__ void cf_step2(f32x2 na, f32x2 cv,
                                         f32x2& cr, f32x2& ci) {
  #pragma clang fp contract(off)
  const f32x2 dr = na - cr;
  const f32x2 di = mk2(1.0f, 1.0f) - ci;
  f32x2 nr_, ni_;
  npdiv2(cv, dr, di, nr_, ni_);
  cr = nr_; ci = ni_;
}

// two independent cheap (rcp) warmup steps, packed. Per-component ops match
// the scalar cheap step exactly (and the 8 exact tail steps contract the
// carry to bit-exact regardless).
__device__ __forceinline__ void cf_cheap2(f32x2 na, f32x2 cv,
                                          f32x2& cr, f32x2& ci) {
  const f32x2 dr = na - cr;
  const f32x2 di = mk2(1.0f, 1.0f) - ci;
  const f32x2 m2 = dr * dr + di * di;
  f32x2 r;
  r[0] = __builtin_amdgcn_rcpf(m2[0]);
  r[1] = __builtin_amdgcn_rcpf(m2[1]);
  const f32x2 t = cv * r;
  cr = dr * t;
  ci = -(di * t);
}

// -------------------------------------------------------------------------

// -(clip(h0_diag + fake_quantize(v), -10, 10)); exact op order.
__device__ __forceinline__ float neg_a(float vv, float hd) {
  #pragma clang fp contract(off)
  float q = rintf(vv);                  // round half-even == np.rint
  q = fminf(fmaxf(q, -128.0f), 127.0f);
  float he = hd + q;
  he = fminf(fmaxf(he, -10.0f), 10.0f);
  return 0.0f - he;                     // Re(z - a)
}

// clip(+-100) -> rint -> clip(+-128); exact ops.
__device__ __forceinline__ float fq_out(float x) {
  #pragma clang fp contract(off)
  x = fminf(fmaxf(x, -100.0f), 100.0f);
  x = rintf(x);
  x = fminf(fmaxf(x, -128.0f), 127.0f);
  return x;
}

// ccf[i] = cc[i-HALO] zero-padded: i in [0, N + 2*HALO + 8)
__global__ void cc_kernel(const float* __restrict__ hsub,
                          const float* __restrict__ hsup,
                          float* __restrict__ ccf, int N) {
  #pragma clang fp contract(off)
  const int i = blockIdx.x * blockDim.x + threadIdx.x;
  if (i < N + 2*HALO + 8) {
    const int k = i - HALO;
    ccf[i] = (k >= 0 && k < N - 1) ? hsub[k] * hsup[k] : 0.0f;
  }
}

// w[0..7] = cc[m0..m0+7], where (m0+HALO) % 4 == 0: two aligned float4 loads.
__device__ __forceinline__ void load8_f(const float4* __restrict__ cc4,
                                        int m0, float* w) {
  const int q = (m0 + HALO) >> 2;
  const float4 A = cc4[q];
  const float4 B = cc4[q + 1];
  w[0]=A.x; w[1]=A.y; w[2]=A.z; w[3]=A.w;
  w[4]=B.x; w[5]=B.y; w[6]=B.z; w[7]=B.w;
}

// w[0..7] = cc[m0..m0+7], where (m0+HALO) % 4 == 3: three aligned float4 loads.
__device__ __forceinline__ void load8_b(const float4* __restrict__ cc4,
                                        int m0, float* w) {
  const int q = (m0 + HALO - 3) >> 2;   // (m0+HALO-3) % 4 == 0
  const float4 A = cc4[q];              // covers m0-3 .. m0
  const float4 B = cc4[q + 1];          // m0+1 .. m0+4
  const float4 C = cc4[q + 2];          // m0+5 .. m0+8
  w[0]=A.w;
  w[1]=B.x; w[2]=B.y; w[3]=B.z; w[4]=B.w;
  w[5]=C.x; w[6]=C.y; w[7]=C.z;
}

__global__ void __launch_bounds__(NTHR)
bk_kernel(const float* __restrict__ v,
          const float* __restrict__ hdiag,
          const float* __restrict__ ccf,      // zero-padded couplings (d_ws)
          float2* __restrict__ out,
          int N, int chunks_per_row, int blocks_per_row) {
  #pragma clang fp contract(off)
  __shared__ float sA[SPAD];            // negA for 4 chunks + halos: ~17.1 KB

  const int tid  = threadIdx.x;
  const int lane = tid & (LANES - 1);
  const int wv   = tid >> 6;
  const int row  = blockIdx.x / blocks_per_row;
  const int cb   = blockIdx.x - row * blocks_per_row;
  const int bbase = cb * BCHUNK;        // first element of the block's span
  const long rowoff = (long)row * N;
  const float4* cc4 = (const float4*)ccf;

  // ---- stage negA for all 4 chunks, 256-wide coalesced; zeros outside [0,N)
  for (int i = tid; i < BSTAGE; i += NTHR) {
    const int k = bbase - HALO + i;
    float na = 0.0f;
    if (k >= 0 && k < N) na = neg_a(v[rowoff + k], hdiag[k]);
    sA[padi(i)] = na;
  }
  __syncthreads();

  const int chunk = cb * WAVES + wv;
  if (chunk < chunks_per_row) {
    const int base = bbase + wv * CHUNK;  // this wave's chunk start
    const int s0  = base + lane * SEG;
    const int s1  = s0 + SEG;
    const int loff = bbase - HALO;        // global index of sA[0]
    const int li0 = s0 - loff;            // sA (unpadded) index of s0

    float Rr[SEG], Ri[SEG];               // R values; recycled per-8 as G
    float wcB[8], wcF[8];                 // cc windows
    float naB8[8], naF8[8];               // batched negA reads

    // ---- paired warmups, PACKED 2-wide ([0]=bwd, [1]=fwd) -----------------
    // bwd: R[k-1] = cc[k-1] / (z - a[k] - R[k]), k = s1+23 .. s1, carry 0.
    // fwd: L[k+1] = cc[k]   / (z - a[k] - L[k]), k = s0-24 .. s0-1, carry 0.
    // Groups g=0,1: cheap rcp steps (pre-merge). g=2: exact Smith tail.
    // All 16 LDS reads of a group issue back-to-back before the steps.
    f32x2 cr2 = mk2(0.0f, 0.0f), ci2 = mk2(0.0f, 0.0f);
    #pragma unroll
    for (int g = 0; g < WARM / 8; ++g) {
      const int kh = s1 + (WARM - 1) - 8 * g;   // bwd group high k
      const int kl = s0 - WARM + 8 * g;         // fwd group low k
      load8_b(cc4, kh - 8, wcB);                // wcB[j'] = cc[kh-8+j']
      load8_f(cc4, kl, wcF);                    // wcF[j]  = cc[kl+j]
      #pragma unroll
      for (int j = 0; j < 8; ++j) {
        naB8[j] = sA[padi(kh - j - loff)];
        naF8[j] = sA[padi(kl + j - loff)];
      }
      #pragma unroll
      for (int j = 0; j < 8; ++j) {
        const f32x2 na2 = mk2(naB8[j], naF8[j]);
        const f32x2 cv2 = mk2(wcB[7 - j], wcF[j]);
        if (g < (WCHEAP / 8)) cf_cheap2(na2, cv2, cr2, ci2);
        else                  cf_step2 (na2, cv2, cr2, ci2);
      }
    }
    float crB = cr2[0], ciB = ci2[0];           // R carry
    float crF = cr2[1], ciF = ci2[1];           // L carry
    Rr[SEG-1] = crB; Ri[SEG-1] = ciB;           // R[15]

    // ---- backward main (scalar serial chain): t = SEG-1 .. 1, store R -----
    #pragma unroll
    for (int tg = 0; tg < SEG / 8; ++tg) {
      const int th = SEG - 1 - 8 * tg;          // high t of this group
      load8_b(cc4, s0 + th - 8, wcB);           // wcB[j'] = cc[s0+th-8+j']
      #pragma unroll
      for (int j = 0; j < 8; ++j)
        naB8[j] = sA[padi(li0 + th - j)];       // na at t = th-j (j=7 unused ok)
      #pragma unroll
      for (int j = 0; j < 8; ++j) {
        const int t = th - j;
        if (t >= 1) {
          cf_step(naB8[j], wcB[7 - j], crB, ciB);   // cc[k-1], k = s0+t
          Rr[t-1] = crB; Ri[t-1] = ciB;
        }
      }
    }

    // ---- forward main: combine||advance PACKED per element ----------------
    // [0] = combine npdiv(1, drf, dif), [1] = advance npdiv(cc, drL, diL);
    // independent, identical op sequence -> v_pk. Per-8 group recycles
    // Rr/Ri[t] in place as fq_out(G) and bursts 64 B immediately (R17).
    float4* op = (float4*)(&out[rowoff + s0]);  // 128-B aligned
    #pragma unroll
    for (int tg = 0; tg < SEG / 8; ++tg) {
      const int kl = s0 + 8 * tg;
      load8_f(cc4, kl, wcF);                    // wcF[j] = cc[kl+j]
      #pragma unroll
      for (int j = 0; j < 8; ++j)
        naF8[j] = sA[padi(li0 + 8 * tg + j)];
      #pragma unroll
      for (int j = 0; j < 8; ++j) {
        const int t = 8 * tg + j;
        const float drL = naF8[j] - crF;        // (z - a) - L
        const float diL = 1.0f - ciF;
        const float drf = drL - Rr[t];          // ... - R
        const float dif = diL - Ri[t];
        if (t < SEG - 1) {
          f32x2 outr, outi;
          npdiv2(mk2(1.0f, wcF[j]),
                 mk2(drf, drL), mk2(dif, diL), outr, outi);
          Rr[t] = fq_out(outr[0]);              // recycle R slot as G out
          Ri[t] = fq_out(outi[0]);
          crF = outr[1]; ciF = outi[1];         // advance L
        } else {                                // t = 15: combine only
          const C2 G = npdiv(1.0f, drf, dif);
          Rr[t] = fq_out(G.r);
          Ri[t] = fq_out(G.i);
        }
      }
      #pragma unroll
      for (int q = 0; q < 4; ++q) {             // burst this group's 64 B
        float4 f4;
        f4.x = Rr[8*tg + 2*q];     f4.y = Ri[8*tg + 2*q];
        f4.z = Rr[8*tg + 2*q + 1]; f4.w = Ri[8*tg + 2*q + 1];
        op[4*tg + q] = f4;
      }
    }
  }
}

extern "C" void kernel_launch(void* const* d_in, const int* in_sizes, int n_in,
                              void* d_out, int out_size, void* d_ws, size_t ws_size,
                              hipStream_t stream) {
  const float* v    = (const float*)d_in[0];
  const float* hd   = (const float*)d_in[1];
  const float* hsub = (const float*)d_in[2];
  const float* hsup = (const float*)d_in[3];
  const int N = in_sizes[1];
  const int B = in_sizes[0] / N;
  const int chunks = (N + CHUNK - 1) / CHUNK;        // 16 for N=16384 (exact)
  const int bpr    = (chunks + WAVES - 1) / WAVES;   // 4 blocks per row

  float* ccf = (float*)d_ws;                     // N + 2*HALO + 8 floats
  const int ccn = N + 2*HALO + 8;
  cc_kernel<<<(ccn + 255) / 256, 256, 0, stream>>>(hsub, hsup, ccf, N);
  bk_kernel<<<B * bpr, NTHR, 0, stream>>>(v, hd, ccf, (float2*)d_out,
                                          N, chunks, bpr);
}